// Round 2
// baseline (719.301 us; speedup 1.0000x reference)
//
#include <hip/hip_runtime.h>
#include <stdint.h>

#define DEVI __device__ __forceinline__

typedef __attribute__((ext_vector_type(4))) int    i32x4;
typedef __attribute__((ext_vector_type(4))) float  f32x4;
typedef __attribute__((ext_vector_type(8))) __bf16 bf16x8;

static constexpr int BB = 4, NN = 2048, KK = 32, PP = NN * KK;  // P per batch
static constexpr float GEPS = 1e-5f;

DEVI unsigned short f2bf(float f) {
  unsigned u = __builtin_bit_cast(unsigned, f);
  return (unsigned short)((u + 0x7FFFu + ((u >> 16) & 1u)) >> 16);
}
DEVI float bf2f(unsigned short h) {
  unsigned u = (unsigned)h << 16;
  return __builtin_bit_cast(float, u);
}
DEVI uint2 pack4(float a, float b, float c, float d) {
  return make_uint2((unsigned)f2bf(a) | ((unsigned)f2bf(b) << 16),
                    (unsigned)f2bf(c) | ((unsigned)f2bf(d) << 16));
}
DEVI void mfma16(f32x4& d, i32x4 a, i32x4 b) {
  // A[m=lane&15][k=8*(lane>>4)+j], B[k][n=lane&15], D[m=(lane>>4)*4+reg][n=lane&15].
  // A/B share the (lane-group, elem)->k map, so internal k-permutation self-cancels.
  d = __builtin_amdgcn_mfma_f32_16x16x32_bf16(
      __builtin_bit_cast(bf16x8, a), __builtin_bit_cast(bf16x8, b), d, 0, 0, 0);
}

// ---------------- prep: convert f32 weights to bf16 ----------------
__global__ void prep_kern(const float* Wfc, const float* Wgc, const float* Wfo,
                          unsigned short* dWfc, unsigned short* dWgc, unsigned short* dWfo) {
  int i = blockIdx.x * 256 + threadIdx.x;
  if (i < 16384)       dWfc[i] = f2bf(Wfc[i]);
  else if (i < 32768)  dWgc[i - 16384] = f2bf(Wgc[i - 16384]);
  else if (i < 98304)  dWfo[i - 32768] = f2bf(Wfo[i - 32768]);
}

// ---------------- generic fused GEMM ----------------
// out[b][p][COUT] (bf16) = act( W[COUT][CIN] @ in[b][CIN][p]  + bias )
// MODE 0: srcA = f32 channel-major input [b][CIN][P] (transposed while staging)
// MODE 1: srcA = r1 bf16 [b][n][128] (broadcast over k), srcB = r2 bf16 [b][p][128],
//         W/bias are per-batch (folded).
template<int CIN, int COUT, int MODE, bool RELU>
__global__ __launch_bounds__(256, 2)
void gemm_kern(const void* srcA, const void* srcB,
               const unsigned short* Wmat, const float* bias,
               unsigned short* out, float* stats, int group_base,
               int P, int tiles_per_b, int nblk) {
  constexpr int MW = COUT / 4;    // o-range per wave
  constexpr int MF = MW / 16;     // m-fragments per wave
  constexpr int KS = CIN / 32;    // k-steps
  constexpr int CINP = CIN + 8;   // padded LDS pitch (shorts) -> 16B-aligned rows
  __shared__ unsigned short tile[64 * CINP];

  const int tid = threadIdx.x;
  const int lane = tid & 63, w = tid >> 6;
  const int l15 = lane & 15, lg = lane >> 4;
  const int b = blockIdx.x / nblk, blk = blockIdx.x % nblk;

  const unsigned short* Wb = (MODE == 1) ? (Wmat + (size_t)b * COUT * CIN) : Wmat;
  const float* biasb = (MODE == 1) ? (bias + b * COUT) : bias;

  // A fragments (weights) resident in registers for the whole block
  i32x4 a[KS][MF];
#pragma unroll
  for (int ks = 0; ks < KS; ++ks)
#pragma unroll
    for (int mf = 0; mf < MF; ++mf)
      a[ks][mf] = *(const i32x4*)(Wb + (size_t)(w * MW + mf * 16 + l15) * CIN + ks * 32 + lg * 8);

  f32x4 bi[MF];
#pragma unroll
  for (int mf = 0; mf < MF; ++mf)
    bi[mf] = *(const f32x4*)(biasb + w * MW + mf * 16 + lg * 4);

  float ssum[MF], ssq[MF];
#pragma unroll
  for (int mf = 0; mf < MF; ++mf) { ssum[mf] = 0.f; ssq[mf] = 0.f; }

  for (int t = blk; t < tiles_per_b; t += nblk) {
    const int p0 = t * 64;
    if (MODE == 0) {
      // stage + transpose: 4x4 f32 blocks per thread, write b64 bf16 rows
      const float* src = (const float*)srcA + (size_t)b * CIN * P + p0;
      const int cq = tid >> 4, pq = tid & 15;
#pragma unroll
      for (int cblk = 0; cblk < CIN; cblk += 64) {
        f32x4 v[4];
#pragma unroll
        for (int i = 0; i < 4; ++i)
          v[i] = *(const f32x4*)(src + (size_t)(cblk + cq * 4 + i) * (size_t)P + pq * 4);
#pragma unroll
        for (int jj = 0; jj < 4; ++jj) {
          uint2 pk = pack4(v[0][jj], v[1][jj], v[2][jj], v[3][jj]);
          *(uint2*)&tile[(pq * 4 + jj) * CINP + cblk + cq * 4] = pk;
        }
      }
    } else {
      const unsigned short* r1 = (const unsigned short*)srcA;
      const unsigned short* r2 = (const unsigned short*)srcB;
      const int cg = tid & 15, pq = tid >> 4;
#pragma unroll
      for (int cblk = 0; cblk < 256; cblk += 64) {
#pragma unroll
        for (int j = 0; j < 4; ++j) {
          int p = pq * 4 + j;
          const unsigned short* sp;
          if (cblk < 128) {
            int n = (p0 + p) >> 5;
            sp = r1 + ((size_t)b * NN + n) * 128 + cblk + cg * 4;
          } else {
            sp = r2 + ((size_t)b * PP + p0 + p) * 128 + (cblk - 128) + cg * 4;
          }
          *(uint2*)&tile[p * CINP + cblk + cg * 4] = *(const uint2*)sp;
        }
      }
    }
    __syncthreads();

    f32x4 acc[MF][4];
#pragma unroll
    for (int mf = 0; mf < MF; ++mf)
#pragma unroll
      for (int nf = 0; nf < 4; ++nf) acc[mf][nf] = f32x4{0.f, 0.f, 0.f, 0.f};

#pragma unroll
    for (int ks = 0; ks < KS; ++ks) {
      i32x4 bfr[4];
#pragma unroll
      for (int nf = 0; nf < 4; ++nf)
        bfr[nf] = *(const i32x4*)&tile[(nf * 16 + l15) * CINP + ks * 32 + lg * 8];
#pragma unroll
      for (int mf = 0; mf < MF; ++mf)
#pragma unroll
        for (int nf = 0; nf < 4; ++nf) mfma16(acc[mf][nf], a[ks][mf], bfr[nf]);
    }
    __syncthreads();  // all waves done reading tile; epilogue is register-only

    // epilogue: bias (+relu), stats partials, packed bf16 store (pos-major)
#pragma unroll
    for (int mf = 0; mf < MF; ++mf) {
      const int o4 = w * MW + mf * 16 + lg * 4;
#pragma unroll
      for (int nf = 0; nf < 4; ++nf) {
        const int p = p0 + nf * 16 + l15;
        float y0 = acc[mf][nf][0] + bi[mf][0];
        float y1 = acc[mf][nf][1] + bi[mf][1];
        float y2 = acc[mf][nf][2] + bi[mf][2];
        float y3 = acc[mf][nf][3] + bi[mf][3];
        if (RELU) {
          y0 = fmaxf(y0, 0.f); y1 = fmaxf(y1, 0.f);
          y2 = fmaxf(y2, 0.f); y3 = fmaxf(y3, 0.f);
        }
        ssum[mf] += y0 + y1 + y2 + y3;
        ssq[mf] += y0 * y0 + y1 * y1 + y2 * y2 + y3 * y3;
        *(uint2*)(out + ((size_t)b * P + p) * COUT + o4) = pack4(y0, y1, y2, y3);
      }
    }
  }

  // block-level stats reduction -> global atomics (f32; threshold tolerant)
#pragma unroll
  for (int mf = 0; mf < MF; ++mf) {
    float s = ssum[mf], q = ssq[mf];
#pragma unroll
    for (int d = 1; d < 16; d <<= 1) { s += __shfl_xor(s, d); q += __shfl_xor(q, d); }
    if (l15 == 0) {
      int g = group_base + ((w * MW + mf * 16 + lg * 4) >> 3);
      atomicAdd(&stats[(b * 32 + g) * 2 + 0], s);
      atomicAdd(&stats[(b * 32 + g) * 2 + 1], q);
    }
  }
}

// ---------------- fold kernels ----------------
__global__ void fold1_kern(const float* st1, const float* g1, const float* be1,
                           const float* W_w1, const float* b_w1,
                           unsigned short* W1p, float* b1p) {
  int b = blockIdx.x, tid = threadIdx.x;
  __shared__ float s_l[256], t_l[256];
  {
    int c = tid, g = c >> 3;
    float cnt = (g < 16) ? (8.f * NN) : (8.f * NN * KK);
    float su = st1[(b * 32 + g) * 2], sq = st1[(b * 32 + g) * 2 + 1];
    float mean = su / cnt;
    float var = fmaxf(sq / cnt - mean * mean, 0.f);
    float s = g1[c] * rsqrtf(var + GEPS);
    s_l[c] = s; t_l[c] = be1[c] - mean * s;
  }
  __syncthreads();
  int o = tid;
  float acc = b_w1[o];
  for (int c = 0; c < 256; ++c) {
    float wv = W_w1[o * 256 + c];
    W1p[((size_t)b * 256 + o) * 256 + c] = f2bf(wv * s_l[c]);
    acc += wv * t_l[c];
  }
  b1p[b * 256 + o] = acc;
}

__global__ void fold23_kern(const float* st2, const float* st3,
                            const float* g2, const float* be2,
                            const float* W_w2, const float* b_w2,
                            const float* g3, const float* be3,
                            unsigned short* W2p, float* b2p, float* s3t3) {
  int b = blockIdx.x, tid = threadIdx.x;
  __shared__ float s_l[256], t_l[256];
  {
    int c = tid, g = c >> 3;
    float cnt = 8.f * NN * KK;
    float su = st2[(b * 32 + g) * 2], sq = st2[(b * 32 + g) * 2 + 1];
    float mean = su / cnt;
    float var = fmaxf(sq / cnt - mean * mean, 0.f);
    float s = g2[c] * rsqrtf(var + GEPS);
    s_l[c] = s; t_l[c] = be2[c] - mean * s;

    float su3 = st3[(b * 32 + g) * 2], sq3 = st3[(b * 32 + g) * 2 + 1];
    float mean3 = su3 / cnt;
    float var3 = fmaxf(sq3 / cnt - mean3 * mean3, 0.f);
    float s3 = g3[c] * rsqrtf(var3 + GEPS);
    s3t3[(b * 256 + c) * 2 + 0] = s3;
    s3t3[(b * 256 + c) * 2 + 1] = be3[c] - mean3 * s3;
  }
  __syncthreads();
  int o = tid;
  float acc = b_w2[o];
  for (int c = 0; c < 256; ++c) {
    float wv = W_w2[o * 256 + c];
    W2p[((size_t)b * 256 + o) * 256 + c] = f2bf(wv * s_l[c]);
    acc += wv * t_l[c];
  }
  b2p[b * 256 + o] = acc;
}

// ---------------- K5: scores GEMM (swapped roles) + masked softmax + weighted sum ----------------
__global__ __launch_bounds__(256, 2)
void k5_kern(const unsigned short* x2t, const unsigned short* gor,
             const unsigned short* W2p, const float* b2p,
             const float* s3t3, const int* count, float* out, int nblk) {
  __shared__ unsigned short xt[64 * 264];
  const int tid = threadIdx.x, lane = tid & 63, w = tid >> 6;
  const int l15 = lane & 15, lg = lane >> 4;
  const int b = blockIdx.x / nblk, blk = blockIdx.x % nblk;

  // W2p as B-operand: D[m=pos][n=o] -> softmax k mostly in-lane
  i32x4 wb[8][4];
  const unsigned short* Wb = W2p + (size_t)b * 65536;
#pragma unroll
  for (int ks = 0; ks < 8; ++ks)
#pragma unroll
    for (int of = 0; of < 4; ++of)
      wb[ks][of] = *(const i32x4*)(Wb + (size_t)(w * 64 + of * 16 + l15) * 256 + ks * 32 + lg * 8);

  float bia[4], s3v[4], t3v[4];
#pragma unroll
  for (int of = 0; of < 4; ++of) {
    int o = w * 64 + of * 16 + l15;
    bia[of] = b2p[b * 256 + o];
    s3v[of] = s3t3[(b * 256 + o) * 2 + 0];
    t3v[of] = s3t3[(b * 256 + o) * 2 + 1];
  }

  const unsigned short* xb = x2t + (size_t)b * PP * 256;
  const unsigned short* gb = gor + (size_t)b * PP * 256;

  for (int t = blk; t < 1024; t += nblk) {
    const int p0 = t * 64, n0 = p0 >> 5;
    {
      const int cg = tid & 15, pq = tid >> 4;
#pragma unroll
      for (int cblk = 0; cblk < 256; cblk += 64)
#pragma unroll
        for (int j = 0; j < 4; ++j) {
          int p = pq * 4 + j;
          *(uint2*)&xt[p * 264 + cblk + cg * 4] =
              *(const uint2*)(xb + (size_t)(p0 + p) * 256 + cblk + cg * 4);
        }
    }
    __syncthreads();

    f32x4 acc[4][4];  // [pf][of]
#pragma unroll
    for (int pf = 0; pf < 4; ++pf)
#pragma unroll
      for (int of = 0; of < 4; ++of) acc[pf][of] = f32x4{0.f, 0.f, 0.f, 0.f};

#pragma unroll
    for (int ks = 0; ks < 8; ++ks) {
      i32x4 af[4];
#pragma unroll
      for (int pf = 0; pf < 4; ++pf)
        af[pf] = *(const i32x4*)&xt[(pf * 16 + l15) * 264 + ks * 32 + lg * 8];
#pragma unroll
      for (int pf = 0; pf < 4; ++pf)
#pragma unroll
        for (int of = 0; of < 4; ++of) mfma16(acc[pf][of], af[pf], wb[ks][of]);
    }
    __syncthreads();

    const int cnt0 = max(count[b * NN + n0], 1);
    const int cnt1 = max(count[b * NN + n0 + 1], 1);
#pragma unroll
    for (int of = 0; of < 4; ++of) {
      const int o = w * 64 + of * 16 + l15;
      float res[2];
#pragma unroll
      for (int pair = 0; pair < 2; ++pair) {
        const int cnt = pair ? cnt1 : cnt0;
        float sc[2][4];
#pragma unroll
        for (int ph = 0; ph < 2; ++ph)
#pragma unroll
          for (int r = 0; r < 4; ++r) {
            int k = ph * 16 + lg * 4 + r;
            float v = acc[pair * 2 + ph][of][r] + bia[of];
            sc[ph][r] = (k < cnt) ? v : -1e9f;
          }
        float m = sc[0][0];
#pragma unroll
        for (int ph = 0; ph < 2; ++ph)
#pragma unroll
          for (int r = 0; r < 4; ++r) m = fmaxf(m, sc[ph][r]);
        m = fmaxf(m, __shfl_xor(m, 16));
        m = fmaxf(m, __shfl_xor(m, 32));
        float den = 0.f, con = 0.f;
#pragma unroll
        for (int ph = 0; ph < 2; ++ph)
#pragma unroll
          for (int r = 0; r < 4; ++r) {
            float e = __expf(sc[ph][r] - m);
            int p = p0 + pair * 32 + ph * 16 + lg * 4 + r;
            float g = bf2f(gb[(size_t)p * 256 + o]);
            g = fmaxf(s3v[of] * g + t3v[of], 0.f);
            den += e; con += e * g;
          }
        den += __shfl_xor(den, 16); con += __shfl_xor(con, 16);
        den += __shfl_xor(den, 32); con += __shfl_xor(con, 32);
        res[pair] = con / den;
      }
      if (lg == 0)
        *(float2*)(out + (size_t)(b * 256 + o) * NN + n0) = make_float2(res[0], res[1]);
    }
  }
}

// ---------------- launch ----------------
extern "C" void kernel_launch(void* const* d_in, const int* in_sizes, int n_in,
                              void* d_out, int out_size, void* d_ws, size_t ws_size,
                              hipStream_t stream) {
  const float* feat = (const float*)d_in[0];
  const float* gf   = (const float*)d_in[1];
  const float* gfo  = (const float*)d_in[2];
  const int*   cnt  = (const int*)d_in[3];
  const float* W_fc = (const float*)d_in[4];
  const float* b_fc = (const float*)d_in[5];
  const float* W_gc = (const float*)d_in[6];
  const float* b_gc = (const float*)d_in[7];
  const float* g1   = (const float*)d_in[8];
  const float* be1  = (const float*)d_in[9];
  const float* W_w1 = (const float*)d_in[10];
  const float* b_w1 = (const float*)d_in[11];
  const float* g2   = (const float*)d_in[12];
  const float* be2  = (const float*)d_in[13];
  const float* W_w2 = (const float*)d_in[14];
  const float* b_w2 = (const float*)d_in[15];
  const float* W_fo = (const float*)d_in[16];
  const float* b_fo = (const float*)d_in[17];
  const float* g3   = (const float*)d_in[18];
  const float* be3  = (const float*)d_in[19];
  float* out = (float*)d_out;
  char* ws = (char*)d_ws;

  constexpr size_t ST1 = 0, ST2 = 1024, ST3 = 2048;
  constexpr size_t WFC = 4096;
  constexpr size_t WGC = WFC + 32768;
  constexpr size_t WFO = WGC + 32768;
  constexpr size_t W1P = WFO + 131072;
  constexpr size_t B1P = W1P + 524288;
  constexpr size_t W2P = B1P + 4096;
  constexpr size_t B2P = W2P + 524288;
  constexpr size_t S3T = B2P + 4096;
  constexpr size_t R1  = 2097152;
  constexpr size_t X2  = R1 + 2097152;
  constexpr size_t R2  = X2 + 134217728;
  constexpr size_t GOR = R2;  // go_raw overwrites r2 (written after K4 consumed r2)
  constexpr size_t WS_NEED = GOR + 134217728;  // 272,629,760 B
  if (ws_size < WS_NEED) return;  // cannot run safely; output stays invalid (signal)

  float* st1 = (float*)(ws + ST1);
  float* st2 = (float*)(ws + ST2);
  float* st3 = (float*)(ws + ST3);
  unsigned short* wfc = (unsigned short*)(ws + WFC);
  unsigned short* wgc = (unsigned short*)(ws + WGC);
  unsigned short* wfo = (unsigned short*)(ws + WFO);
  unsigned short* w1p = (unsigned short*)(ws + W1P);
  float* b1p = (float*)(ws + B1P);
  unsigned short* w2p = (unsigned short*)(ws + W2P);
  float* b2p = (float*)(ws + B2P);
  float* s3t = (float*)(ws + S3T);
  unsigned short* r1 = (unsigned short*)(ws + R1);
  unsigned short* x2 = (unsigned short*)(ws + X2);
  unsigned short* r2 = (unsigned short*)(ws + R2);
  unsigned short* gor = (unsigned short*)(ws + GOR);

  hipMemsetAsync(ws, 0, 3072, stream);  // zero stats accumulators
  prep_kern<<<384, 256, 0, stream>>>(W_fc, W_gc, W_fo, wfc, wgc, wfo);

  // K1: feat1 = relu(W_fc@feat+b) -> r1 [b][n][128], stats1 groups 0..15
  gemm_kern<128, 128, 0, true><<<dim3(4 * 32), 256, 0, stream>>>(
      feat, nullptr, wfc, b_fc, r1, st1, 0, NN, NN / 64, 32);
  // K2: gfeat1 = relu(W_gc@gf+b) -> r2 [b][p][128], stats1 groups 16..31
  gemm_kern<128, 128, 0, true><<<dim3(4 * 128), 256, 0, stream>>>(
      gf, nullptr, wgc, b_gc, r2, st1, 16, PP, PP / 64, 128);

  fold1_kern<<<4, 256, 0, stream>>>(st1, g1, be1, W_w1, b_w1, w1p, b1p);

  // K4: x2 = relu(W1'(GN1-folded) @ concat(r1,r2)) -> x2, stats2
  gemm_kern<256, 256, 1, true><<<dim3(4 * 128), 256, 0, stream>>>(
      r1, r2, w1p, b1p, x2, st2, 0, PP, PP / 64, 128);

  // K3: go_raw = W_fo@gfo+b (no relu) -> gor (overwrites r2), stats3 on raw
  gemm_kern<256, 256, 0, false><<<dim3(4 * 128), 256, 0, stream>>>(
      gfo, nullptr, wfo, b_fo, gor, st3, 0, PP, PP / 64, 128);

  fold23_kern<<<4, 256, 0, stream>>>(st2, st3, g2, be2, W_w2, b_w2, g3, be3, w2p, b2p, s3t);

  // K5: scores (GN2-folded) + mask + softmax + sum_k relu(GN3(go))*w -> out
  k5_kern<<<dim3(4 * 128), 256, 0, stream>>>(x2, gor, w2p, b2p, s3t, cnt, out, 128);
}